// Round 5
// baseline (150.399 us; speedup 1.0000x reference)
//
#include <hip/hip_runtime.h>

// Problem constants (fixed by setup_inputs):
//   x: (64,1,8,8) f32 = 16 KB TOTAL; KH=KW=5 -> oh=ow=4
//   rows n = b*16 + s, s = oy*4+ox, N = 1024; feat[n,k] = x[b*64+(oy+i)*8+(ox+j)], k=i*5+j
//   idx0:(128,36,6) in [0,25), lut0:(128,36,64)
//   idx1:(128, 6,6) in [0,36), lut1:(128, 6,64)
//   idx2:(128, 1,6) in [0, 6), lut2:(128, 1,64)
//   out[b,t,oy,ox] = b*2048 + t*16 + s
#define T_TREES 128
#define M0 36
#define M1 6
#define NROWS 1024
#define XPAD 68   // image stride in LDS: 68%32=4 -> 4 b-groups land on 2 bank sets (2-way = free)

__device__ __forceinline__ float sigmoidf(float v) {
    return 1.f / (1.f + __expf(-v));
}

// Trilinear-factorized contraction; P in registers (static indexing only).
__device__ __forceinline__ float lut_node(const float* __restrict__ P,
                                          float a, float b, float c,
                                          float d, float e, float f) {
    float wa[4] = {(1.f - a) * (1.f - b), (1.f - a) * b, a * (1.f - b), a * b};
    float wb[4] = {(1.f - c) * (1.f - d), (1.f - c) * d, c * (1.f - d), c * d};
    float wc[4] = {(1.f - e) * (1.f - f), (1.f - e) * f, e * (1.f - f), e * f};
    float acc = 0.f;
#pragma unroll
    for (int p = 0; p < 4; ++p) {
        float tp = 0.f;
#pragma unroll
        for (int q = 0; q < 4; ++q) {
            const float* Pq = P + p * 16 + q * 4;
            float tq = Pq[0] * wc[0] + Pq[1] * wc[1] + Pq[2] * wc[2] + Pq[3] * wc[3];
            tp += tq * wb[q];
        }
        acc += tp * wa[p];
    }
    return acc;
}

// ===== layer 0: wave-stationary — wave w owns node (t, mg*4+w) for ALL 1024
// rows (16 rows/thread). P loaded to regs ONCE per 16 row-nodes -> LDS pipe
// ~46 cy/row-node < VALU ~55 cy. 1152 blocks, 4 waves, ~1.1 occupancy passes.
__global__ __launch_bounds__(256, 4) void l0_kernel(
    const float* __restrict__ x, const int* __restrict__ idx0,
    const float* __restrict__ lut0, float* __restrict__ h0) {
    __shared__ float xs[64 * XPAD];          // 17408 B, padded image stride
    __shared__ __align__(16) float Ps[4 * 64];

    const int tid = threadIdx.x;
    const int bx = blockIdx.x;               // bx = mg*128 + t (t fast -> XCD locality)
    const int t = bx & 127;
    const int mg = bx >> 7;                  // node group [0,9)

    // stage x with padded stride (coalesced read; LDS write conflict-free)
    for (int i = tid; i < 4096; i += 256)
        xs[(i >> 6) * XPAD + (i & 63)] = x[i];
    // stage sigmoid(P) for this block's 4 nodes (tid spans 4*64 exactly)
    Ps[tid] = sigmoidf(lut0[(t * M0 + mg * 4) * 64 + tid]);
    __syncthreads();

    const int w = tid >> 6, ln = tid & 63;
    const int m = mg * 4 + w;

    // hoist this wave's P into 64 registers (row-invariant)
    float P[64];
#pragma unroll
    for (int i = 0; i < 16; ++i) {
        float4 v = reinterpret_cast<const float4*>(Ps + w * 64)[i];
        P[4 * i] = v.x; P[4 * i + 1] = v.y; P[4 * i + 2] = v.z; P[4 * i + 3] = v.w;
    }

    // wave-uniform idx -> padded window offsets
    const int* id = idx0 + (t * M0 + m) * 6;
    int di[6];
#pragma unroll
    for (int j = 0; j < 6; ++j) {
        int k = id[j];
        int ii = (k * 13) >> 6;              // k/5 for k in [0,25)
        di[j] = k - 5 * ii + ii * 8;         // i*8 + j (unpadded col offset)
    }

    float* __restrict__ hout = h0 + (t * M0 + m) * NROWS;
#pragma unroll 4
    for (int u = 0; u < 16; ++u) {
        int row = u * 64 + ln;
        int b = row >> 4, s = row & 15;
        int xb = b * XPAD + (s >> 2) * 8 + (s & 3);
        hout[row] = lut_node(P, xs[xb + di[0]], xs[xb + di[1]], xs[xb + di[2]],
                                xs[xb + di[3]], xs[xb + di[4]], xs[xb + di[5]]);
    }
}

// ===== layers 1+2 fused: block = (t, half of rows). Waves 0-5 = layer-1
// nodes (8 rows/thread, P in regs, h0 gathers coalesced L2-hits); barrier;
// first 256 threads do layer 2 from LDS h1.
__global__ __launch_bounds__(384) void l12_kernel(
    const float* __restrict__ h0, const int* __restrict__ idx1,
    const float* __restrict__ lut1, const int* __restrict__ idx2,
    const float* __restrict__ lut2, float* __restrict__ out) {
    __shared__ __align__(16) float Ps[(M1 + 1) * 64];   // 448 floats
    __shared__ float h1s[M1 * 512];                     // 12 KB

    const int tid = threadIdx.x;
    const int bx = blockIdx.x;               // bx = half*128 + t
    const int t = bx & 127;
    const int half = bx >> 7;

    for (int i = tid; i < (M1 + 1) * 64; i += 384) {
        float v = (i < M1 * 64) ? lut1[t * (M1 * 64) + i] : lut2[t * 64 + (i - M1 * 64)];
        Ps[i] = sigmoidf(v);
    }
    __syncthreads();

    const int w = tid >> 6, ln = tid & 63;

    // layer 1: wave w = node w of tree t over 512 rows
    {
        float P[64];
#pragma unroll
        for (int i = 0; i < 16; ++i) {
            float4 v = reinterpret_cast<const float4*>(Ps + w * 64)[i];
            P[4 * i] = v.x; P[4 * i + 1] = v.y; P[4 * i + 2] = v.z; P[4 * i + 3] = v.w;
        }
        const int* id = idx1 + (t * M1 + w) * 6;
        int c0 = (t * M0 + id[0]) * NROWS, c1 = (t * M0 + id[1]) * NROWS;
        int c2 = (t * M0 + id[2]) * NROWS, c3 = (t * M0 + id[3]) * NROWS;
        int c4 = (t * M0 + id[4]) * NROWS, c5 = (t * M0 + id[5]) * NROWS;
#pragma unroll 2
        for (int u = 0; u < 8; ++u) {
            int rl = u * 64 + ln;
            int row = half * 512 + rl;
            h1s[w * 512 + rl] = lut_node(P, h0[c0 + row], h0[c1 + row], h0[c2 + row],
                                            h0[c3 + row], h0[c4 + row], h0[c5 + row]);
        }
    }
    __syncthreads();

    // layer 2: 256 threads x 2 rows
    if (tid < 256) {
        float P[64];
#pragma unroll
        for (int i = 0; i < 16; ++i) {
            float4 v = reinterpret_cast<const float4*>(Ps + M1 * 64)[i];
            P[4 * i] = v.x; P[4 * i + 1] = v.y; P[4 * i + 2] = v.z; P[4 * i + 3] = v.w;
        }
        const int* id = idx2 + t * 6;
        int e0 = id[0] * 512, e1 = id[1] * 512, e2 = id[2] * 512;
        int e3 = id[3] * 512, e4 = id[4] * 512, e5 = id[5] * 512;
#pragma unroll
        for (int u = 0; u < 2; ++u) {
            int rl = u * 256 + tid;
            int row = half * 512 + rl;
            float o = lut_node(P, h1s[e0 + rl], h1s[e1 + rl], h1s[e2 + rl],
                                  h1s[e3 + rl], h1s[e4 + rl], h1s[e5 + rl]);
            int b = row >> 4, s = row & 15;
            out[b * (T_TREES * 16) + t * 16 + s] = o;
        }
    }
}

// ===== fallback (ws too small): self-contained single kernel =====
__global__ __launch_bounds__(128) void clut_fb_kernel(
    const float* __restrict__ x,
    const int* __restrict__ idx0, const float* __restrict__ lut0,
    const int* __restrict__ idx1, const float* __restrict__ lut1,
    const int* __restrict__ idx2, const float* __restrict__ lut2,
    float* __restrict__ out) {
    __shared__ __align__(16) float slut[43 * 64];
    __shared__ float feat[25 * 128];
    __shared__ float h0[M0 * 128];
    __shared__ float h1[M1 * 128];

    const int tid = threadIdx.x;
    const int t = blockIdx.y;
    for (int i = tid; i < 43 * 64; i += 128) {
        float v;
        if (i < M0 * 64)              v = lut0[t * (M0 * 64) + i];
        else if (i < (M0 + M1) * 64)  v = lut1[t * (M1 * 64) + (i - M0 * 64)];
        else                          v = lut2[t * 64 + (i - (M0 + M1) * 64)];
        slut[i] = sigmoidf(v);
    }
    const int n = blockIdx.x * 128 + tid;
    const int b = n >> 4, s = n & 15;
    const float* xb = x + b * 64 + (s >> 2) * 8 + (s & 3);
#pragma unroll
    for (int i = 0; i < 5; ++i)
#pragma unroll
        for (int j = 0; j < 5; ++j)
            feat[(i * 5 + j) * 128 + tid] = xb[i * 8 + j];
    __syncthreads();
    for (int m = 0; m < M0; ++m) {
        const int* id = idx0 + (t * M0 + m) * 6;
        h0[m * 128 + tid] = lut_node(slut + m * 64,
            feat[id[0] * 128 + tid], feat[id[1] * 128 + tid], feat[id[2] * 128 + tid],
            feat[id[3] * 128 + tid], feat[id[4] * 128 + tid], feat[id[5] * 128 + tid]);
    }
    for (int m = 0; m < M1; ++m) {
        const int* id = idx1 + (t * M1 + m) * 6;
        h1[m * 128 + tid] = lut_node(slut + (M0 + m) * 64,
            h0[id[0] * 128 + tid], h0[id[1] * 128 + tid], h0[id[2] * 128 + tid],
            h0[id[3] * 128 + tid], h0[id[4] * 128 + tid], h0[id[5] * 128 + tid]);
    }
    {
        const int* id = idx2 + t * 6;
        float o = lut_node(slut + (M0 + M1) * 64,
            h1[id[0] * 128 + tid], h1[id[1] * 128 + tid], h1[id[2] * 128 + tid],
            h1[id[3] * 128 + tid], h1[id[4] * 128 + tid], h1[id[5] * 128 + tid]);
        out[b * (T_TREES * 16) + t * 16 + s] = o;
    }
}

extern "C" void kernel_launch(void* const* d_in, const int* in_sizes, int n_in,
                              void* d_out, int out_size, void* d_ws, size_t ws_size,
                              hipStream_t stream) {
    const float* x    = (const float*)d_in[0];
    const int*   idx0 = (const int*)  d_in[1];
    const float* lut0 = (const float*)d_in[2];
    const int*   idx1 = (const int*)  d_in[3];
    const float* lut1 = (const float*)d_in[4];
    const int*   idx2 = (const int*)  d_in[5];
    const float* lut2 = (const float*)d_in[6];
    float* out = (float*)d_out;

    const size_t h0_bytes = (size_t)T_TREES * M0 * NROWS * sizeof(float);  // 18.9 MB
    if (ws_size >= h0_bytes) {
        float* h0 = (float*)d_ws;
        l0_kernel<<<dim3((M0 / 4) * T_TREES), 256, 0, stream>>>(x, idx0, lut0, h0);   // 1152 blocks
        l12_kernel<<<dim3(2 * T_TREES), 384, 0, stream>>>(h0, idx1, lut1, idx2, lut2, out);  // 256 blocks
    } else {
        dim3 grid(NROWS / 128, T_TREES);
        clut_fb_kernel<<<grid, 128, 0, stream>>>(x, idx0, lut0, idx1, lut1, idx2, lut2, out);
    }
}

// Round 6
// 29.203 us; speedup vs baseline: 5.1501x; 5.1501x over previous
//
#include <hip/hip_runtime.h>

// Problem constants (fixed by setup_inputs):
//   x: (64,1,8,8) f32 = 16 KB TOTAL; KH=KW=5 -> oh=ow=4
//   rows n = b*16 + s, s = oy*4+ox, N = 1024; feat[n,k] = x[b*64+(oy+i)*8+(ox+j)], k=i*5+j
//   idx0:(128,36,6) in [0,25), lut0:(128,36,64)
//   idx1:(128, 6,6) in [0,36), lut1:(128, 6,64)
//   idx2:(128, 1,6) in [0, 6), lut2:(128, 1,64)
//   out[b,t,oy,ox] = b*2048 + t*16 + s
#define T_TREES 128
#define M0 36
#define M1 6
#define NROWS 1024
#define XPAD 68   // LDS image stride: breaks the %32==0 bank pattern across b-groups

__device__ __forceinline__ float sigmoidf(float v) {
    return 1.f / (1.f + __expf(-v));
}

// Trilinear-factorized contraction; P in registers (static indexing only).
__device__ __forceinline__ float lut_node(const float* __restrict__ P,
                                          float a, float b, float c,
                                          float d, float e, float f) {
    float wa[4] = {(1.f - a) * (1.f - b), (1.f - a) * b, a * (1.f - b), a * b};
    float wb[4] = {(1.f - c) * (1.f - d), (1.f - c) * d, c * (1.f - d), c * d};
    float wc[4] = {(1.f - e) * (1.f - f), (1.f - e) * f, e * (1.f - f), e * f};
    float acc = 0.f;
#pragma unroll
    for (int p = 0; p < 4; ++p) {
        float tp = 0.f;
#pragma unroll
        for (int q = 0; q < 4; ++q) {
            const float* Pq = P + p * 16 + q * 4;
            float tq = Pq[0] * wc[0] + Pq[1] * wc[1] + Pq[2] * wc[2] + Pq[3] * wc[3];
            tp += tq * wb[q];
        }
        acc += tp * wa[p];
    }
    return acc;
}

// ===== layer 0: wave-stationary — wave w owns node (t, mg*4+w) for ALL 1024
// rows (16 rows/thread), so the 16 ds_read_b128 P-loads amortize 16x.
// NO min-occupancy clamp: the body needs ~64(P)+2x25(rows in flight) live
// VGPRs; clamping to 128 (R5's ",4") made the allocator spill P to scratch
// (309 MB FETCH, 6% VALUBusy). ILP > occupancy here.
__global__ __launch_bounds__(256) void l0_kernel(
    const float* __restrict__ x, const int* __restrict__ idx0,
    const float* __restrict__ lut0, float* __restrict__ h0) {
    __shared__ float xs[64 * XPAD];          // 17408 B, padded image stride
    __shared__ __align__(16) float Ps[4 * 64];

    const int tid = threadIdx.x;
    const int bx = blockIdx.x;               // bx = mg*128 + t (t fast -> XCD locality)
    const int t = bx & 127;
    const int mg = bx >> 7;                  // node group [0,9)

    // stage x with padded stride (coalesced read; conflict-free write)
    for (int i = tid; i < 4096; i += 256)
        xs[(i >> 6) * XPAD + (i & 63)] = x[i];
    // stage sigmoid(P) for this block's 4 consecutive nodes (tid spans 4*64)
    Ps[tid] = sigmoidf(lut0[(t * M0 + mg * 4) * 64 + tid]);
    __syncthreads();

    const int w = tid >> 6, ln = tid & 63;
    const int m = mg * 4 + w;

    // hoist this wave's P into 64 registers (row-invariant)
    float P[64];
#pragma unroll
    for (int i = 0; i < 16; ++i) {
        float4 v = reinterpret_cast<const float4*>(Ps + w * 64)[i];
        P[4 * i] = v.x; P[4 * i + 1] = v.y; P[4 * i + 2] = v.z; P[4 * i + 3] = v.w;
    }

    // wave-uniform idx -> window offsets (scalar loads)
    const int* id = idx0 + (t * M0 + m) * 6;
    int di[6];
#pragma unroll
    for (int j = 0; j < 6; ++j) {
        int k = id[j];
        int ii = (k * 13) >> 6;              // k/5 for k in [0,25)
        di[j] = k - 5 * ii + ii * 8;         // i*8 + j
    }

    float* __restrict__ hout = h0 + (t * M0 + m) * NROWS;
#pragma unroll 2
    for (int u = 0; u < 16; ++u) {
        int row = u * 64 + ln;
        int b = row >> 4, s = row & 15;
        int xb = b * XPAD + (s >> 2) * 8 + (s & 3);
        hout[row] = lut_node(P, xs[xb + di[0]], xs[xb + di[1]], xs[xb + di[2]],
                                xs[xb + di[3]], xs[xb + di[4]], xs[xb + di[5]]);
    }
}

// ===== layers 1+2 fused: block = (t, half of rows). Waves 0-5 = layer-1
// nodes (8 rows/thread, P in regs, coalesced h0 reads, L2/XCD-local since
// writer blocks mg*128+t and reader blocks half*128+t agree mod 8); then
// first 256 threads do layer 2 from LDS h1.
__global__ __launch_bounds__(384) void l12_kernel(
    const float* __restrict__ h0, const int* __restrict__ idx1,
    const float* __restrict__ lut1, const int* __restrict__ idx2,
    const float* __restrict__ lut2, float* __restrict__ out) {
    __shared__ __align__(16) float Ps[(M1 + 1) * 64];   // 448 floats
    __shared__ float h1s[M1 * 512];                     // 12 KB

    const int tid = threadIdx.x;
    const int bx = blockIdx.x;               // bx = half*128 + t
    const int t = bx & 127;
    const int half = bx >> 7;

    for (int i = tid; i < (M1 + 1) * 64; i += 384) {
        float v = (i < M1 * 64) ? lut1[t * (M1 * 64) + i] : lut2[t * 64 + (i - M1 * 64)];
        Ps[i] = sigmoidf(v);
    }
    __syncthreads();

    const int w = tid >> 6, ln = tid & 63;

    // layer 1: wave w = node w of tree t over 512 rows
    {
        float P[64];
#pragma unroll
        for (int i = 0; i < 16; ++i) {
            float4 v = reinterpret_cast<const float4*>(Ps + w * 64)[i];
            P[4 * i] = v.x; P[4 * i + 1] = v.y; P[4 * i + 2] = v.z; P[4 * i + 3] = v.w;
        }
        const int* id = idx1 + (t * M1 + w) * 6;
        int c0 = (t * M0 + id[0]) * NROWS, c1 = (t * M0 + id[1]) * NROWS;
        int c2 = (t * M0 + id[2]) * NROWS, c3 = (t * M0 + id[3]) * NROWS;
        int c4 = (t * M0 + id[4]) * NROWS, c5 = (t * M0 + id[5]) * NROWS;
#pragma unroll 2
        for (int u = 0; u < 8; ++u) {
            int rl = u * 64 + ln;
            int row = half * 512 + rl;
            h1s[w * 512 + rl] = lut_node(P, h0[c0 + row], h0[c1 + row], h0[c2 + row],
                                            h0[c3 + row], h0[c4 + row], h0[c5 + row]);
        }
    }
    __syncthreads();

    // layer 2: 256 threads x 2 rows
    if (tid < 256) {
        float P[64];
#pragma unroll
        for (int i = 0; i < 16; ++i) {
            float4 v = reinterpret_cast<const float4*>(Ps + M1 * 64)[i];
            P[4 * i] = v.x; P[4 * i + 1] = v.y; P[4 * i + 2] = v.z; P[4 * i + 3] = v.w;
        }
        const int* id = idx2 + t * 6;
        int e0 = id[0] * 512, e1 = id[1] * 512, e2 = id[2] * 512;
        int e3 = id[3] * 512, e4 = id[4] * 512, e5 = id[5] * 512;
#pragma unroll
        for (int u = 0; u < 2; ++u) {
            int rl = u * 256 + tid;
            int row = half * 512 + rl;
            float o = lut_node(P, h1s[e0 + rl], h1s[e1 + rl], h1s[e2 + rl],
                                  h1s[e3 + rl], h1s[e4 + rl], h1s[e5 + rl]);
            int b = row >> 4, s = row & 15;
            out[b * (T_TREES * 16) + t * 16 + s] = o;
        }
    }
}

// ===== fallback (ws too small): self-contained single kernel =====
__global__ __launch_bounds__(128) void clut_fb_kernel(
    const float* __restrict__ x,
    const int* __restrict__ idx0, const float* __restrict__ lut0,
    const int* __restrict__ idx1, const float* __restrict__ lut1,
    const int* __restrict__ idx2, const float* __restrict__ lut2,
    float* __restrict__ out) {
    __shared__ __align__(16) float slut[43 * 64];
    __shared__ float feat[25 * 128];
    __shared__ float h0[M0 * 128];
    __shared__ float h1[M1 * 128];

    const int tid = threadIdx.x;
    const int t = blockIdx.y;
    for (int i = tid; i < 43 * 64; i += 128) {
        float v;
        if (i < M0 * 64)              v = lut0[t * (M0 * 64) + i];
        else if (i < (M0 + M1) * 64)  v = lut1[t * (M1 * 64) + (i - M0 * 64)];
        else                          v = lut2[t * 64 + (i - (M0 + M1) * 64)];
        slut[i] = sigmoidf(v);
    }
    const int n = blockIdx.x * 128 + tid;
    const int b = n >> 4, s = n & 15;
    const float* xb = x + b * 64 + (s >> 2) * 8 + (s & 3);
#pragma unroll
    for (int i = 0; i < 5; ++i)
#pragma unroll
        for (int j = 0; j < 5; ++j)
            feat[(i * 5 + j) * 128 + tid] = xb[i * 8 + j];
    __syncthreads();
    for (int m = 0; m < M0; ++m) {
        const int* id = idx0 + (t * M0 + m) * 6;
        h0[m * 128 + tid] = lut_node(slut + m * 64,
            feat[id[0] * 128 + tid], feat[id[1] * 128 + tid], feat[id[2] * 128 + tid],
            feat[id[3] * 128 + tid], feat[id[4] * 128 + tid], feat[id[5] * 128 + tid]);
    }
    for (int m = 0; m < M1; ++m) {
        const int* id = idx1 + (t * M1 + m) * 6;
        h1[m * 128 + tid] = lut_node(slut + (M0 + m) * 64,
            h0[id[0] * 128 + tid], h0[id[1] * 128 + tid], h0[id[2] * 128 + tid],
            h0[id[3] * 128 + tid], h0[id[4] * 128 + tid], h0[id[5] * 128 + tid]);
    }
    {
        const int* id = idx2 + t * 6;
        float o = lut_node(slut + (M0 + M1) * 64,
            h1[id[0] * 128 + tid], h1[id[1] * 128 + tid], h1[id[2] * 128 + tid],
            h1[id[3] * 128 + tid], h1[id[4] * 128 + tid], h1[id[5] * 128 + tid]);
        out[b * (T_TREES * 16) + t * 16 + s] = o;
    }
}

extern "C" void kernel_launch(void* const* d_in, const int* in_sizes, int n_in,
                              void* d_out, int out_size, void* d_ws, size_t ws_size,
                              hipStream_t stream) {
    const float* x    = (const float*)d_in[0];
    const int*   idx0 = (const int*)  d_in[1];
    const float* lut0 = (const float*)d_in[2];
    const int*   idx1 = (const int*)  d_in[3];
    const float* lut1 = (const float*)d_in[4];
    const int*   idx2 = (const int*)  d_in[5];
    const float* lut2 = (const float*)d_in[6];
    float* out = (float*)d_out;

    const size_t h0_bytes = (size_t)T_TREES * M0 * NROWS * sizeof(float);  // 18.9 MB
    if (ws_size >= h0_bytes) {
        float* h0 = (float*)d_ws;
        l0_kernel<<<dim3((M0 / 4) * T_TREES), 256, 0, stream>>>(x, idx0, lut0, h0);   // 1152 blocks
        l12_kernel<<<dim3(2 * T_TREES), 384, 0, stream>>>(h0, idx1, lut1, idx2, lut2, out);  // 256 blocks
    } else {
        dim3 grid(NROWS / 128, T_TREES);
        clut_fb_kernel<<<grid, 128, 0, stream>>>(x, idx0, lut0, idx1, lut1, idx2, lut2, out);
    }
}

// Round 7
// 25.166 us; speedup vs baseline: 5.9763x; 1.1604x over previous
//
#include <hip/hip_runtime.h>

// Problem constants (fixed by setup_inputs):
//   x: (64,1,8,8) f32 = 16 KB TOTAL; KH=KW=5 -> oh=ow=4
//   rows n = b*16 + s, s = oy*4+ox, N = 1024; feat[n,k] = x[b*64+(oy+i)*8+(ox+j)], k=i*5+j
//   idx0:(128,36,6) in [0,25), lut0:(128,36,64)
//   idx1:(128, 6,6) in [0,36), lut1:(128, 6,64)
//   idx2:(128, 1,6) in [0, 6), lut2:(128, 1,64)
//   out[b,t,oy,ox] = b*2048 + t*16 + s
#define T_TREES 128
#define M0 36
#define M1 6
#define NROWS 1024
#define XPAD 68   // LDS image stride (floats): 68%32=4 -> max 2 lanes/bank (free); 272B = 16B-aligned

__device__ __forceinline__ float sigmoidf(float v) {
    return 1.f / (1.f + __expf(-v));
}

// Trilinear-factorized contraction; P in registers (static indexing only).
__device__ __forceinline__ float lut_node(const float* __restrict__ P,
                                          float a, float b, float c,
                                          float d, float e, float f) {
    float wa[4] = {(1.f - a) * (1.f - b), (1.f - a) * b, a * (1.f - b), a * b};
    float wb[4] = {(1.f - c) * (1.f - d), (1.f - c) * d, c * (1.f - d), c * d};
    float wc[4] = {(1.f - e) * (1.f - f), (1.f - e) * f, e * (1.f - f), e * f};
    float acc = 0.f;
#pragma unroll
    for (int p = 0; p < 4; ++p) {
        float tp = 0.f;
#pragma unroll
        for (int q = 0; q < 4; ++q) {
            const float* Pq = P + p * 16 + q * 4;
            float tq = Pq[0] * wc[0] + Pq[1] * wc[1] + Pq[2] * wc[2] + Pq[3] * wc[3];
            tp += tq * wb[q];
        }
        acc += tp * wa[p];
    }
    return acc;
}

// ===== layer 0: wave-stationary — wave w owns node (t, mg*4+w) for ALL 1024
// rows (16 rows/thread): one x-staging + one P-hoist amortized over 16
// row-evals. unroll 4 -> 24 gathers in flight (R4's proven ILP level).
// (256,1): explicit 512-VGPR budget — R5 showed what a clamp-induced P spill
// does (309 MB scratch FETCH); R6 may have spilled mildly at default budget.
__global__ __launch_bounds__(256, 1) void l0_kernel(
    const float* __restrict__ x, const int* __restrict__ idx0,
    const float* __restrict__ lut0, float* __restrict__ h0) {
    __shared__ float xs[64 * XPAD];          // 17408 B, padded image stride
    __shared__ __align__(16) float Ps[4 * 64];

    const int tid = threadIdx.x;
    const int bx = blockIdx.x;               // bx = mg*128 + t (t fast -> XCD locality)
    const int t = bx & 127;
    const int mg = bx >> 7;                  // node group [0,9)

    // stage x: 4 float4 per thread, issued first so L2 latency overlaps sigmoid
    float4 xv[4];
#pragma unroll
    for (int k = 0; k < 4; ++k)
        xv[k] = reinterpret_cast<const float4*>(x)[tid + k * 256];
    float pv = sigmoidf(lut0[(t * M0 + mg * 4) * 64 + tid]);  // tid spans 4 nodes x 64
#pragma unroll
    for (int k = 0; k < 4; ++k) {
        int i4 = tid + k * 256;              // float4 index into x (16 per image)
        *reinterpret_cast<float4*>(xs + (i4 >> 4) * XPAD + (i4 & 15) * 4) = xv[k];
    }
    Ps[tid] = pv;
    __syncthreads();

    const int w = tid >> 6, ln = tid & 63;
    const int m = mg * 4 + w;

    // hoist this wave's P into 64 registers (row-invariant, broadcast reads)
    float P[64];
#pragma unroll
    for (int i = 0; i < 16; ++i) {
        float4 v = reinterpret_cast<const float4*>(Ps + w * 64)[i];
        P[4 * i] = v.x; P[4 * i + 1] = v.y; P[4 * i + 2] = v.z; P[4 * i + 3] = v.w;
    }

    // wave-uniform idx -> window offsets (scalar loads)
    const int* id = idx0 + (t * M0 + m) * 6;
    int di[6];
#pragma unroll
    for (int j = 0; j < 6; ++j) {
        int k = id[j];
        int ii = (k * 13) >> 6;              // k/5 for k in [0,25)
        di[j] = k - 5 * ii + ii * 8;         // i*8 + j
    }

    float* __restrict__ hout = h0 + (t * M0 + m) * NROWS;
#pragma unroll 4
    for (int u = 0; u < 16; ++u) {
        int row = u * 64 + ln;
        int b = u * 4 + (ln >> 4), s = ln & 15;
        int xb = b * XPAD + (s >> 2) * 8 + (s & 3);
        hout[row] = lut_node(P, xs[xb + di[0]], xs[xb + di[1]], xs[xb + di[2]],
                                xs[xb + di[3]], xs[xb + di[4]], xs[xb + di[5]]);
    }
}

// ===== layers 1+2 fused: block = (t, quarter of rows), 512 blocks (2/CU,
// single pass, ~5 waves/SIMD for L2-latency hiding). Waves 0-5 = layer-1
// nodes (node-stationary, P in regs, coalesced h0 reads, XCD-local: writer
// blocks mg*128+t and reader blocks q*128+t agree mod 8); then first 256
// threads do layer 2 from LDS h1.
__global__ __launch_bounds__(384) void l12_kernel(
    const float* __restrict__ h0, const int* __restrict__ idx1,
    const float* __restrict__ lut1, const int* __restrict__ idx2,
    const float* __restrict__ lut2, float* __restrict__ out) {
    __shared__ __align__(16) float Ps[(M1 + 1) * 64];   // 448 floats
    __shared__ float h1s[M1 * 256];                     // 6 KB

    const int tid = threadIdx.x;
    const int bx = blockIdx.x;               // bx = q*128 + t
    const int t = bx & 127;
    const int q = bx >> 7;                   // row quarter [0,4)

    for (int i = tid; i < (M1 + 1) * 64; i += 384) {
        float v = (i < M1 * 64) ? lut1[t * (M1 * 64) + i] : lut2[t * 64 + (i - M1 * 64)];
        Ps[i] = sigmoidf(v);
    }
    __syncthreads();

    const int w = tid >> 6, ln = tid & 63;

    // layer 1: wave w = node w of tree t over 256 rows (4 rows/thread)
    {
        float P[64];
#pragma unroll
        for (int i = 0; i < 16; ++i) {
            float4 v = reinterpret_cast<const float4*>(Ps + w * 64)[i];
            P[4 * i] = v.x; P[4 * i + 1] = v.y; P[4 * i + 2] = v.z; P[4 * i + 3] = v.w;
        }
        const int* id = idx1 + (t * M1 + w) * 6;
        int c0 = (t * M0 + id[0]) * NROWS, c1 = (t * M0 + id[1]) * NROWS;
        int c2 = (t * M0 + id[2]) * NROWS, c3 = (t * M0 + id[3]) * NROWS;
        int c4 = (t * M0 + id[4]) * NROWS, c5 = (t * M0 + id[5]) * NROWS;
#pragma unroll
        for (int u = 0; u < 4; ++u) {
            int rl = u * 64 + ln;
            int row = q * 256 + rl;
            h1s[w * 256 + rl] = lut_node(P, h0[c0 + row], h0[c1 + row], h0[c2 + row],
                                            h0[c3 + row], h0[c4 + row], h0[c5 + row]);
        }
    }
    __syncthreads();

    // layer 2: 256 threads x 1 row
    if (tid < 256) {
        float P[64];
#pragma unroll
        for (int i = 0; i < 16; ++i) {
            float4 v = reinterpret_cast<const float4*>(Ps + M1 * 64)[i];
            P[4 * i] = v.x; P[4 * i + 1] = v.y; P[4 * i + 2] = v.z; P[4 * i + 3] = v.w;
        }
        const int* id = idx2 + t * 6;
        float o = lut_node(P, h1s[id[0] * 256 + tid], h1s[id[1] * 256 + tid],
                              h1s[id[2] * 256 + tid], h1s[id[3] * 256 + tid],
                              h1s[id[4] * 256 + tid], h1s[id[5] * 256 + tid]);
        int row = q * 256 + tid;
        int b = row >> 4, s = row & 15;
        out[b * (T_TREES * 16) + t * 16 + s] = o;
    }
}

// ===== fallback (ws too small): self-contained single kernel =====
__global__ __launch_bounds__(128) void clut_fb_kernel(
    const float* __restrict__ x,
    const int* __restrict__ idx0, const float* __restrict__ lut0,
    const int* __restrict__ idx1, const float* __restrict__ lut1,
    const int* __restrict__ idx2, const float* __restrict__ lut2,
    float* __restrict__ out) {
    __shared__ __align__(16) float slut[43 * 64];
    __shared__ float feat[25 * 128];
    __shared__ float h0[M0 * 128];
    __shared__ float h1[M1 * 128];

    const int tid = threadIdx.x;
    const int t = blockIdx.y;
    for (int i = tid; i < 43 * 64; i += 128) {
        float v;
        if (i < M0 * 64)              v = lut0[t * (M0 * 64) + i];
        else if (i < (M0 + M1) * 64)  v = lut1[t * (M1 * 64) + (i - M0 * 64)];
        else                          v = lut2[t * 64 + (i - (M0 + M1) * 64)];
        slut[i] = sigmoidf(v);
    }
    const int n = blockIdx.x * 128 + tid;
    const int b = n >> 4, s = n & 15;
    const float* xb = x + b * 64 + (s >> 2) * 8 + (s & 3);
#pragma unroll
    for (int i = 0; i < 5; ++i)
#pragma unroll
        for (int j = 0; j < 5; ++j)
            feat[(i * 5 + j) * 128 + tid] = xb[i * 8 + j];
    __syncthreads();
    for (int m = 0; m < M0; ++m) {
        const int* id = idx0 + (t * M0 + m) * 6;
        h0[m * 128 + tid] = lut_node(slut + m * 64,
            feat[id[0] * 128 + tid], feat[id[1] * 128 + tid], feat[id[2] * 128 + tid],
            feat[id[3] * 128 + tid], feat[id[4] * 128 + tid], feat[id[5] * 128 + tid]);
    }
    for (int m = 0; m < M1; ++m) {
        const int* id = idx1 + (t * M1 + m) * 6;
        h1[m * 128 + tid] = lut_node(slut + (M0 + m) * 64,
            h0[id[0] * 128 + tid], h0[id[1] * 128 + tid], h0[id[2] * 128 + tid],
            h0[id[3] * 128 + tid], h0[id[4] * 128 + tid], h0[id[5] * 128 + tid]);
    }
    {
        const int* id = idx2 + t * 6;
        float o = lut_node(slut + (M0 + M1) * 64,
            h1[id[0] * 128 + tid], h1[id[1] * 128 + tid], h1[id[2] * 128 + tid],
            h1[id[3] * 128 + tid], h1[id[4] * 128 + tid], h1[id[5] * 128 + tid]);
        out[b * (T_TREES * 16) + t * 16 + s] = o;
    }
}

extern "C" void kernel_launch(void* const* d_in, const int* in_sizes, int n_in,
                              void* d_out, int out_size, void* d_ws, size_t ws_size,
                              hipStream_t stream) {
    const float* x    = (const float*)d_in[0];
    const int*   idx0 = (const int*)  d_in[1];
    const float* lut0 = (const float*)d_in[2];
    const int*   idx1 = (const int*)  d_in[3];
    const float* lut1 = (const float*)d_in[4];
    const int*   idx2 = (const int*)  d_in[5];
    const float* lut2 = (const float*)d_in[6];
    float* out = (float*)d_out;

    const size_t h0_bytes = (size_t)T_TREES * M0 * NROWS * sizeof(float);  // 18.9 MB
    if (ws_size >= h0_bytes) {
        float* h0 = (float*)d_ws;
        l0_kernel<<<dim3((M0 / 4) * T_TREES), 256, 0, stream>>>(x, idx0, lut0, h0);       // 1152 blocks
        l12_kernel<<<dim3(4 * T_TREES), 384, 0, stream>>>(h0, idx1, lut1, idx2, lut2, out); // 512 blocks
    } else {
        dim3 grid(NROWS / 128, T_TREES);
        clut_fb_kernel<<<grid, 128, 0, stream>>>(x, idx0, lut0, idx1, lut1, idx2, lut2, out);
    }
}

// Round 8
// 24.631 us; speedup vs baseline: 6.1061x; 1.0217x over previous
//
#include <hip/hip_runtime.h>

// Problem constants (fixed by setup_inputs):
//   x: (64,1,8,8) f32 = 16 KB TOTAL; KH=KW=5 -> oh=ow=4
//   rows n = b*16 + s, s = oy*4+ox, N = 1024; feat[n,k] = x[b*64+(oy+i)*8+(ox+j)], k=i*5+j
//   idx0:(128,36,6) in [0,25), lut0:(128,36,64)
//   idx1:(128, 6,6) in [0,36), lut1:(128, 6,64)
//   idx2:(128, 1,6) in [0, 6), lut2:(128, 1,64)
//   out[b,t,oy,ox] = b*2048 + t*16 + s
#define T_TREES 128
#define M0 36
#define M1 6
#define NROWS 1024
// XPAD must be ODD: within a wave the gather images step by XPAD and the even
// row-positions cover residues {0,2} mod 8; odd XPAD sweeps all residues mod 8
// -> exactly 2 lanes/bank (free). Even XPAD=68 would give 4-way conflicts.
#define XPAD 67

typedef float v2f __attribute__((ext_vector_type(2)));

__device__ __forceinline__ float sigmoidf(float v) {
    return 1.f / (1.f + __expf(-v));
}

// Pair-weight in FMA-lean form: {(1-a)(1-b),(1-a)b,a(1-b),ab} per 2-row lane.
__device__ __forceinline__ void pair_w(v2f a, v2f b, v2f w[4]) {
    v2f ab = a * b;
    w[3] = ab;
    w[2] = a - ab;
    w[1] = b - ab;
    w[0] = (1.f - a) - w[1];
}

// Trilinear-factorized contraction over a 2-row pair; P scalar regs (row-inv).
__device__ __forceinline__ v2f lut_node_v2(const float* __restrict__ P,
                                           v2f a, v2f b, v2f c,
                                           v2f d, v2f e, v2f f) {
    v2f wa[4], wb[4], wc[4];
    pair_w(a, b, wa);
    pair_w(c, d, wb);
    pair_w(e, f, wc);
    v2f acc = {0.f, 0.f};
#pragma unroll
    for (int p = 0; p < 4; ++p) {
        v2f tp = {0.f, 0.f};
#pragma unroll
        for (int q = 0; q < 4; ++q) {
            const float* Pq = P + p * 16 + q * 4;
            v2f tq = Pq[0] * wc[0] + Pq[1] * wc[1] + Pq[2] * wc[2] + Pq[3] * wc[3];
            tp += tq * wb[q];
        }
        acc += tp * wa[p];
    }
    return acc;
}

// ===== layer 0: wave-stationary node, row-PAIR per lane =====
// Wave w owns node (t, mg*4+w) for all 1024 rows = 8 pairs/lane. Rows 2k,2k+1
// differ only in ox -> features at CONSECUTIVE LDS dwords: the two scalar
// reads fuse into one ds_read2_b32 (4B-aligned ok). Math is 2-wide v2f ->
// packed v_pk_* where the backend supports it. P in 64 regs, hoisted once.
__global__ __launch_bounds__(256, 1) void l0_kernel(
    const float* __restrict__ x, const int* __restrict__ idx0,
    const float* __restrict__ lut0, float* __restrict__ h0) {
    __shared__ float xs[64 * XPAD];          // 17152 B, odd image stride
    __shared__ __align__(16) float Ps[4 * 64];

    const int tid = threadIdx.x;
    const int bx = blockIdx.x;               // bx = mg*128 + t (t fast -> XCD locality)
    const int t = bx & 127;
    const int mg = bx >> 7;                  // node group [0,9)

    // stage x (coalesced float4 reads; scalar LDS writes, odd stride)
#pragma unroll
    for (int k = 0; k < 4; ++k) {
        int i4 = tid + k * 256;              // float4 index (16 per image)
        float4 v = reinterpret_cast<const float4*>(x)[i4];
        float* dst = xs + (i4 >> 4) * XPAD + (i4 & 15) * 4;
        dst[0] = v.x; dst[1] = v.y; dst[2] = v.z; dst[3] = v.w;
    }
    Ps[tid] = sigmoidf(lut0[(t * M0 + mg * 4) * 64 + tid]);  // 4 nodes x 64
    __syncthreads();

    const int w = tid >> 6, ln = tid & 63;
    const int m = mg * 4 + w;

    // hoist this wave's P into 64 registers (broadcast reads, row-invariant)
    float P[64];
#pragma unroll
    for (int i = 0; i < 16; ++i) {
        float4 v = reinterpret_cast<const float4*>(Ps + w * 64)[i];
        P[4 * i] = v.x; P[4 * i + 1] = v.y; P[4 * i + 2] = v.z; P[4 * i + 3] = v.w;
    }

    // wave-uniform idx -> window offsets (scalar loads)
    const int* id = idx0 + (t * M0 + m) * 6;
    int di[6];
#pragma unroll
    for (int j = 0; j < 6; ++j) {
        int k = id[j];
        int ii = (k * 13) >> 6;              // k/5 for k in [0,25)
        di[j] = k - 5 * ii + ii * 8;         // i*8 + j
    }

    float* __restrict__ hout = h0 + (t * M0 + m) * NROWS;
#pragma unroll 2
    for (int u = 0; u < 8; ++u) {
        int p = u * 64 + ln;                 // pair id in [0,512): rows 2p,2p+1
        int b = p >> 3;                      // image
        int s = (p & 7) * 2;                 // even position
        int xb = b * XPAD + (s >> 2) * 8 + (s & 3);
        v2f g[6];
#pragma unroll
        for (int j = 0; j < 6; ++j) {
            int a0 = xb + di[j];
            g[j].x = xs[a0];                 // fuse -> ds_read2_b32
            g[j].y = xs[a0 + 1];
        }
        v2f r = lut_node_v2(P, g[0], g[1], g[2], g[3], g[4], g[5]);
        *reinterpret_cast<v2f*>(hout + 2 * p) = r;   // global_store_dwordx2
    }
}

// ===== layers 1+2 fused: block = (t, quarter of rows), 512 blocks.
// Waves 0-5 = layer-1 nodes over 256 rows = 2 pairs/lane; h0 pair-loads are
// 8B-aligned dwordx2 (XCD-local: writer mg*128+t, reader q*128+t agree mod 8).
// Then 128 threads do layer 2, one pair each, from LDS h1.
__global__ __launch_bounds__(384) void l12_kernel(
    const float* __restrict__ h0, const int* __restrict__ idx1,
    const float* __restrict__ lut1, const int* __restrict__ idx2,
    const float* __restrict__ lut2, float* __restrict__ out) {
    __shared__ __align__(16) float Ps[(M1 + 1) * 64];   // 448 floats
    __shared__ __align__(8) float h1s[M1 * 256];        // 6 KB

    const int tid = threadIdx.x;
    const int bx = blockIdx.x;               // bx = q*128 + t
    const int t = bx & 127;
    const int q = bx >> 7;                   // row quarter [0,4)

    for (int i = tid; i < (M1 + 1) * 64; i += 384) {
        float v = (i < M1 * 64) ? lut1[t * (M1 * 64) + i] : lut2[t * 64 + (i - M1 * 64)];
        Ps[i] = sigmoidf(v);
    }
    __syncthreads();

    const int w = tid >> 6, ln = tid & 63;

    // layer 1: wave w = node w of tree t over 256 rows (2 pairs/lane)
    {
        float P[64];
#pragma unroll
        for (int i = 0; i < 16; ++i) {
            float4 v = reinterpret_cast<const float4*>(Ps + w * 64)[i];
            P[4 * i] = v.x; P[4 * i + 1] = v.y; P[4 * i + 2] = v.z; P[4 * i + 3] = v.w;
        }
        const int* id = idx1 + (t * M1 + w) * 6;
        const float* c0 = h0 + (t * M0 + id[0]) * NROWS;
        const float* c1 = h0 + (t * M0 + id[1]) * NROWS;
        const float* c2 = h0 + (t * M0 + id[2]) * NROWS;
        const float* c3 = h0 + (t * M0 + id[3]) * NROWS;
        const float* c4 = h0 + (t * M0 + id[4]) * NROWS;
        const float* c5 = h0 + (t * M0 + id[5]) * NROWS;
#pragma unroll
        for (int u = 0; u < 2; ++u) {
            int pl = u * 64 + ln;            // pair within quarter [0,128)
            int rr = q * 256 + 2 * pl;       // global row (even)
            v2f r = lut_node_v2(P,
                *reinterpret_cast<const v2f*>(c0 + rr),
                *reinterpret_cast<const v2f*>(c1 + rr),
                *reinterpret_cast<const v2f*>(c2 + rr),
                *reinterpret_cast<const v2f*>(c3 + rr),
                *reinterpret_cast<const v2f*>(c4 + rr),
                *reinterpret_cast<const v2f*>(c5 + rr));
            *reinterpret_cast<v2f*>(h1s + w * 256 + 2 * pl) = r;
        }
    }
    __syncthreads();

    // layer 2: 128 threads, one pair each
    if (tid < 128) {
        float P[64];
#pragma unroll
        for (int i = 0; i < 16; ++i) {
            float4 v = reinterpret_cast<const float4*>(Ps + M1 * 64)[i];
            P[4 * i] = v.x; P[4 * i + 1] = v.y; P[4 * i + 2] = v.z; P[4 * i + 3] = v.w;
        }
        const int* id = idx2 + t * 6;
        int rl = 2 * tid;                    // even row within quarter
        v2f r = lut_node_v2(P,
            *reinterpret_cast<const v2f*>(h1s + id[0] * 256 + rl),
            *reinterpret_cast<const v2f*>(h1s + id[1] * 256 + rl),
            *reinterpret_cast<const v2f*>(h1s + id[2] * 256 + rl),
            *reinterpret_cast<const v2f*>(h1s + id[3] * 256 + rl),
            *reinterpret_cast<const v2f*>(h1s + id[4] * 256 + rl),
            *reinterpret_cast<const v2f*>(h1s + id[5] * 256 + rl));
        int row = q * 256 + rl;
        int b = row >> 4, s = row & 15;
        *reinterpret_cast<v2f*>(out + b * (T_TREES * 16) + t * 16 + s) = r;
    }
}

// ===== fallback (ws too small): self-contained single kernel =====
__global__ __launch_bounds__(128) void clut_fb_kernel(
    const float* __restrict__ x,
    const int* __restrict__ idx0, const float* __restrict__ lut0,
    const int* __restrict__ idx1, const float* __restrict__ lut1,
    const int* __restrict__ idx2, const float* __restrict__ lut2,
    float* __restrict__ out) {
    __shared__ __align__(16) float slut[43 * 64];
    __shared__ float feat[25 * 128];
    __shared__ float h0[M0 * 128];
    __shared__ float h1[M1 * 128];

    const int tid = threadIdx.x;
    const int t = blockIdx.y;
    for (int i = tid; i < 43 * 64; i += 128) {
        float v;
        if (i < M0 * 64)              v = lut0[t * (M0 * 64) + i];
        else if (i < (M0 + M1) * 64)  v = lut1[t * (M1 * 64) + (i - M0 * 64)];
        else                          v = lut2[t * 64 + (i - (M0 + M1) * 64)];
        slut[i] = sigmoidf(v);
    }
    const int n = blockIdx.x * 128 + tid;
    const int b = n >> 4, s = n & 15;
    const float* xb = x + b * 64 + (s >> 2) * 8 + (s & 3);
#pragma unroll
    for (int i = 0; i < 5; ++i)
#pragma unroll
        for (int j = 0; j < 5; ++j)
            feat[(i * 5 + j) * 128 + tid] = xb[i * 8 + j];
    __syncthreads();
    for (int m = 0; m < M0; ++m) {
        const int* id = idx0 + (t * M0 + m) * 6;
        v2f g[6];
#pragma unroll
        for (int j = 0; j < 6; ++j) { g[j].x = feat[id[j] * 128 + tid]; g[j].y = 0.f; }
        v2f r = lut_node_v2(slut + m * 64, g[0], g[1], g[2], g[3], g[4], g[5]);
        h0[m * 128 + tid] = r.x;
    }
    for (int m = 0; m < M1; ++m) {
        const int* id = idx1 + (t * M1 + m) * 6;
        v2f g[6];
#pragma unroll
        for (int j = 0; j < 6; ++j) { g[j].x = h0[id[j] * 128 + tid]; g[j].y = 0.f; }
        v2f r = lut_node_v2(slut + (M0 + m) * 64, g[0], g[1], g[2], g[3], g[4], g[5]);
        h1[m * 128 + tid] = r.x;
    }
    {
        const int* id = idx2 + t * 6;
        v2f g[6];
#pragma unroll
        for (int j = 0; j < 6; ++j) { g[j].x = h1[id[j] * 128 + tid]; g[j].y = 0.f; }
        v2f r = lut_node_v2(slut + (M0 + M1) * 64, g[0], g[1], g[2], g[3], g[4], g[5]);
        out[b * (T_TREES * 16) + t * 16 + s] = r.x;
    }
}

extern "C" void kernel_launch(void* const* d_in, const int* in_sizes, int n_in,
                              void* d_out, int out_size, void* d_ws, size_t ws_size,
                              hipStream_t stream) {
    const float* x    = (const float*)d_in[0];
    const int*   idx0 = (const int*)  d_in[1];
    const float* lut0 = (const float*)d_in[2];
    const int*   idx1 = (const int*)  d_in[3];
    const float* lut1 = (const float*)d_in[4];
    const int*   idx2 = (const int*)  d_in[5];
    const float* lut2 = (const float*)d_in[6];
    float* out = (float*)d_out;

    const size_t h0_bytes = (size_t)T_TREES * M0 * NROWS * sizeof(float);  // 18.9 MB
    if (ws_size >= h0_bytes) {
        float* h0 = (float*)d_ws;
        l0_kernel<<<dim3((M0 / 4) * T_TREES), 256, 0, stream>>>(x, idx0, lut0, h0);       // 1152 blocks
        l12_kernel<<<dim3(4 * T_TREES), 384, 0, stream>>>(h0, idx1, lut1, idx2, lut2, out); // 512 blocks
    } else {
        dim3 grid(NROWS / 128, T_TREES);
        clut_fb_kernel<<<grid, 128, 0, stream>>>(x, idx0, lut0, idx1, lut1, idx2, lut2, out);
    }
}